// Round 1
// baseline (19053.720 us; speedup 1.0000x reference)
//
#include <hip/hip_runtime.h>
#include <math.h>

// Problem dims
#define NV 4096   // vocab
#define NE 256    // emb
#define NH 512    // hidden
#define NB 64     // batch
#define NT 1024   // seq len
#define NG 2048   // 4*NH

// Workspace layout (float offsets)
//  emb_proj : [4096][2048]  = 8388608
//  W_pack   : [128][2048][4]= 1048576   (W_hh repacked for coalesced k4 loads)
//  hs       : [1024][64][512] rows r=t*64+b = 33554432
//  c_buf    : [64][512]     = 32768
//  part     : [65536][32][2]= 4194304   (per-tile argmax partials: val,idx)
#define WS_EMBPROJ ((size_t)0)
#define WS_WPACK   ((size_t)8388608)
#define WS_HS      (WS_WPACK + 1048576)
#define WS_CBUF    (WS_HS + 33554432)
#define WS_PART    (WS_CBUF + 32768)
// total = 47218688 floats ~= 189 MB

// ---------------------------------------------------------------------------
// K0a: emb_proj[v][g] = sum_e emb[v][e]*W_ih[g][e] + b_ih[g] + b_hh[g]
// 128x128 tile, 256 threads, 8x8 micro, K=256 in chunks of 64.
// grid (32, 16)
// ---------------------------------------------------------------------------
__global__ __launch_bounds__(256) void k_embproj(
    const float* __restrict__ emb,    // [4096][256]
    const float* __restrict__ W_ih,   // [2048][256]
    const float* __restrict__ b_ih,
    const float* __restrict__ b_hh,
    float* __restrict__ emb_proj)     // [4096][2048]
{
    __shared__ float Ash[64 * 128];
    __shared__ float Bsh[64 * 128];
    const int tid = threadIdx.x;
    const int rbase = blockIdx.x * 128;
    const int cbase = blockIdx.y * 128;
    const int tx = tid & 15, ty = tid >> 4;
    const int r_l = tid >> 1, half = tid & 1;

    float acc[8][8];
#pragma unroll
    for (int i = 0; i < 8; i++)
#pragma unroll
        for (int j = 0; j < 8; j++) acc[i][j] = 0.f;

    for (int kc = 0; kc < NE; kc += 64) {
        const float* sa = emb + (size_t)(rbase + r_l) * NE + kc + half * 32;
        const float* sb = W_ih + (size_t)(cbase + r_l) * NE + kc + half * 32;
#pragma unroll
        for (int u = 0; u < 8; u++) {
            float4 va = *(const float4*)(sa + 4 * u);
            float4 vb = *(const float4*)(sb + 4 * u);
            int k = half * 32 + 4 * u;
            Ash[(k + 0) * 128 + r_l] = va.x;
            Ash[(k + 1) * 128 + r_l] = va.y;
            Ash[(k + 2) * 128 + r_l] = va.z;
            Ash[(k + 3) * 128 + r_l] = va.w;
            Bsh[(k + 0) * 128 + r_l] = vb.x;
            Bsh[(k + 1) * 128 + r_l] = vb.y;
            Bsh[(k + 2) * 128 + r_l] = vb.z;
            Bsh[(k + 3) * 128 + r_l] = vb.w;
        }
        __syncthreads();
#pragma unroll 4
        for (int k = 0; k < 64; k++) {
            float4 a0 = *(const float4*)&Ash[k * 128 + ty * 8];
            float4 a1 = *(const float4*)&Ash[k * 128 + ty * 8 + 4];
            float4 b0 = *(const float4*)&Bsh[k * 128 + tx * 8];
            float4 b1 = *(const float4*)&Bsh[k * 128 + tx * 8 + 4];
            float a[8] = {a0.x, a0.y, a0.z, a0.w, a1.x, a1.y, a1.z, a1.w};
            float b[8] = {b0.x, b0.y, b0.z, b0.w, b1.x, b1.y, b1.z, b1.w};
#pragma unroll
            for (int i = 0; i < 8; i++)
#pragma unroll
                for (int j = 0; j < 8; j++) acc[i][j] += a[i] * b[j];
        }
        __syncthreads();
    }

    float bias[8];
#pragma unroll
    for (int j = 0; j < 8; j++)
        bias[j] = b_ih[cbase + tx * 8 + j] + b_hh[cbase + tx * 8 + j];
#pragma unroll
    for (int i = 0; i < 8; i++) {
        int row = rbase + ty * 8 + i;
        float* dst = emb_proj + (size_t)row * NG + cbase + tx * 8;
        float4 o0 = make_float4(acc[i][0] + bias[0], acc[i][1] + bias[1],
                                acc[i][2] + bias[2], acc[i][3] + bias[3]);
        float4 o1 = make_float4(acc[i][4] + bias[4], acc[i][5] + bias[5],
                                acc[i][6] + bias[6], acc[i][7] + bias[7]);
        *(float4*)(dst) = o0;
        *(float4*)(dst + 4) = o1;
    }
}

// ---------------------------------------------------------------------------
// K0b: repack W_hh[g][k] -> W_pack[(k>>2)][g][k&3] so that a wave with
// lane=g can load float4 of 4 consecutive k fully coalesced.
// grid 4096 x 256
// ---------------------------------------------------------------------------
__global__ __launch_bounds__(256) void k_pack(
    const float* __restrict__ W_hh, float* __restrict__ W_pack)
{
    int n = blockIdx.x * 256 + threadIdx.x;  // over 2048*512
    int g = n >> 9, k = n & 511;
    W_pack[((size_t)(k >> 2) * NG + g) * 4 + (k & 3)] = W_hh[n];
}

// ---------------------------------------------------------------------------
// K2: one LSTM timestep.
// grid (8 bt, 32 kt) x 512 threads. WG: b in [bt*8,bt*8+8), k-positions
// [kt*16,kt*16+16) -> 64 gate columns {q*512 + kt*16 + j}.
// Wave q owns k-slice [q*64, q*64+64) and all 8 b (partial dots),
// reduction through LDS, then 128 threads do the gate nonlinearity.
// ---------------------------------------------------------------------------
__global__ __launch_bounds__(512) void k_lstm_step(
    const float* __restrict__ emb_proj,  // [4096][2048] (bias folded in)
    const float* __restrict__ W_pack,    // [128][2048][4]
    const int* __restrict__ x,           // [64][1024]
    float* __restrict__ hs,              // rows r=t*64+b, [r][512]
    float* __restrict__ c_buf,           // [64][512]
    int t)
{
    __shared__ float gate_s[8 * 64 * 9];
    const int tid = threadIdx.x;
    const int q = tid >> 6;          // wave id 0..7
    const int lane = tid & 63;
    const int bt = blockIdx.x;       // 0..7
    const int kt = blockIdx.y;       // 0..31
    const int gq = lane >> 4, gj = lane & 15;
    const int g = gq * 512 + kt * 16 + gj;   // gate column 0..2047

    float acc[8];
#pragma unroll
    for (int b = 0; b < 8; b++) acc[b] = 0.f;

    if (t > 0) {
        const float* hbase = hs + (size_t)(t - 1) * (NB * NH) + (size_t)(bt * 8) * NH;
        const float* wbase = W_pack + ((size_t)(q * 16) * NG + g) * 4;
#pragma unroll 4
        for (int kk = 0; kk < 16; kk++) {
            float4 w = *(const float4*)(wbase + (size_t)kk * NG * 4);
            const int k0 = (q * 16 + kk) * 4;
#pragma unroll
            for (int b = 0; b < 8; b++) {
                float4 h4 = *(const float4*)(hbase + b * NH + k0);
                acc[b] += h4.x * w.x + h4.y * w.y + h4.z * w.z + h4.w * w.w;
            }
        }
    }
#pragma unroll
    for (int b = 0; b < 8; b++) gate_s[(q * 64 + lane) * 9 + b] = acc[b];
    __syncthreads();

    if (tid < 128) {
        const int b = tid >> 4, j = tid & 15;
        const int bg = bt * 8 + b;
        const int row = x[bg * NT + t];
        const float* xp = emb_proj + (size_t)row * NG + kt * 16 + j;
        float gr[4];
#pragma unroll
        for (int r = 0; r < 4; r++) {
            float s = xp[r * 512];
#pragma unroll
            for (int qq = 0; qq < 8; qq++)
                s += gate_s[(qq * 64 + r * 16 + j) * 9 + b];
            gr[r] = s;
        }
        float ig = 1.f / (1.f + expf(-gr[0]));
        float fg = 1.f / (1.f + expf(-gr[1]));
        float gg = tanhf(gr[2]);
        float og = 1.f / (1.f + expf(-gr[3]));
        const int idx = bg * NH + kt * 16 + j;
        float c_old = (t > 0) ? c_buf[idx] : 0.f;
        float c = fg * c_old + ig * gg;
        c_buf[idx] = c;
        hs[(size_t)t * (NB * NH) + idx] = og * tanhf(c);
    }
}

// ---------------------------------------------------------------------------
// K3: logits[r][v] = hs[r][:] . W_proj[v][:] + b_proj[v]; write to d_out at
// out_row=(r&63)*1024+(r>>6); also per-tile argmax partials (first-max ties).
// 128x128 tile, 256 thr, 8x8 micro, K=512 in chunks of 64. grid (512, 32)
// ---------------------------------------------------------------------------
__global__ __launch_bounds__(256) void k_logits(
    const float* __restrict__ hs,      // [65536][512]
    const float* __restrict__ W_proj,  // [4096][512]
    const float* __restrict__ b_proj,  // [4096]
    float* __restrict__ logits_out,    // [64][1024][4096]
    float* __restrict__ part)          // [65536][32][2]
{
    __shared__ float smem[2 * 64 * 128];
    float* Ash = smem;
    float* Bsh = smem + 64 * 128;
    const int tid = threadIdx.x;
    const int rbase = blockIdx.x * 128;
    const int cbase = blockIdx.y * 128;
    const int tx = tid & 15, ty = tid >> 4;
    const int r_l = tid >> 1, half = tid & 1;

    float acc[8][8];
#pragma unroll
    for (int i = 0; i < 8; i++)
#pragma unroll
        for (int j = 0; j < 8; j++) acc[i][j] = 0.f;

    for (int kc = 0; kc < NH; kc += 64) {
        const float* sa = hs + (size_t)(rbase + r_l) * NH + kc + half * 32;
        const float* sb = W_proj + (size_t)(cbase + r_l) * NH + kc + half * 32;
#pragma unroll
        for (int u = 0; u < 8; u++) {
            float4 va = *(const float4*)(sa + 4 * u);
            float4 vb = *(const float4*)(sb + 4 * u);
            int k = half * 32 + 4 * u;
            Ash[(k + 0) * 128 + r_l] = va.x;
            Ash[(k + 1) * 128 + r_l] = va.y;
            Ash[(k + 2) * 128 + r_l] = va.z;
            Ash[(k + 3) * 128 + r_l] = va.w;
            Bsh[(k + 0) * 128 + r_l] = vb.x;
            Bsh[(k + 1) * 128 + r_l] = vb.y;
            Bsh[(k + 2) * 128 + r_l] = vb.z;
            Bsh[(k + 3) * 128 + r_l] = vb.w;
        }
        __syncthreads();
#pragma unroll 4
        for (int k = 0; k < 64; k++) {
            float4 a0 = *(const float4*)&Ash[k * 128 + ty * 8];
            float4 a1 = *(const float4*)&Ash[k * 128 + ty * 8 + 4];
            float4 b0 = *(const float4*)&Bsh[k * 128 + tx * 8];
            float4 b1 = *(const float4*)&Bsh[k * 128 + tx * 8 + 4];
            float a[8] = {a0.x, a0.y, a0.z, a0.w, a1.x, a1.y, a1.z, a1.w};
            float b[8] = {b0.x, b0.y, b0.z, b0.w, b1.x, b1.y, b1.z, b1.w};
#pragma unroll
            for (int i = 0; i < 8; i++)
#pragma unroll
                for (int j = 0; j < 8; j++) acc[i][j] += a[i] * b[j];
        }
        __syncthreads();
    }

    float bias[8];
#pragma unroll
    for (int j = 0; j < 8; j++) bias[j] = b_proj[cbase + tx * 8 + j];

    float bestv[8];
    int besti[8];
#pragma unroll
    for (int i = 0; i < 8; i++) {
        int r = rbase + ty * 8 + i;
        int out_row = (r & 63) * NT + (r >> 6);   // b*1024 + t
        float* dst = logits_out + (size_t)out_row * NV + cbase + tx * 8;
        float v[8];
#pragma unroll
        for (int j = 0; j < 8; j++) v[j] = acc[i][j] + bias[j];
        *(float4*)(dst) = make_float4(v[0], v[1], v[2], v[3]);
        *(float4*)(dst + 4) = make_float4(v[4], v[5], v[6], v[7]);
        float bv = v[0];
        int bi = 0;
#pragma unroll
        for (int j = 1; j < 8; j++)
            if (v[j] > bv) { bv = v[j]; bi = j; }
        bestv[i] = bv;
        besti[i] = cbase + tx * 8 + bi;
    }
    __syncthreads();  // done with Ash/Bsh; reuse as reduction scratch
    float* redv = smem;             // [128][17]
    float* redi = smem + 128 * 17;  // [128][17]
#pragma unroll
    for (int i = 0; i < 8; i++) {
        redv[(ty * 8 + i) * 17 + tx] = bestv[i];
        redi[(ty * 8 + i) * 17 + tx] = (float)besti[i];
    }
    __syncthreads();
    if (tid < 128) {
        float bv = -INFINITY;
        float bi = 0.f;
#pragma unroll
        for (int c = 0; c < 16; c++) {
            float v = redv[tid * 17 + c];
            if (v > bv) { bv = v; bi = redi[tid * 17 + c]; }
        }
        int r = rbase + tid;
        part[((size_t)r * 32 + blockIdx.y) * 2] = bv;
        part[((size_t)r * 32 + blockIdx.y) * 2 + 1] = bi;
    }
}

// ---------------------------------------------------------------------------
// K4: reduce 32 column-tile partials per row -> y_pred (float index).
// Ascending tile order + strict > matches np.argmax first-max tie rule.
// grid 256 x 256
// ---------------------------------------------------------------------------
__global__ __launch_bounds__(256) void k_argmax(
    const float* __restrict__ part, float* __restrict__ ypred)
{
    int r = blockIdx.x * 256 + threadIdx.x;  // 0..65535, r = t*64+b
    const float* p = part + (size_t)r * 64;
    float best = -INFINITY, bidx = 0.f;
#pragma unroll 8
    for (int c = 0; c < 32; c++) {
        float v = p[2 * c];
        if (v > best) { best = v; bidx = p[2 * c + 1]; }
    }
    int b = r & 63, t = r >> 6;
    ypred[b * NT + t] = bidx;
}

// ---------------------------------------------------------------------------
extern "C" void kernel_launch(void* const* d_in, const int* in_sizes, int n_in,
                              void* d_out, int out_size, void* d_ws, size_t ws_size,
                              hipStream_t stream)
{
    const int*   x      = (const int*)d_in[0];
    // d_in[1] = lens : unused by the reference computation
    const float* emb    = (const float*)d_in[2];
    const float* W_ih   = (const float*)d_in[3];
    const float* W_hh   = (const float*)d_in[4];
    const float* b_ih   = (const float*)d_in[5];
    const float* b_hh   = (const float*)d_in[6];
    const float* W_proj = (const float*)d_in[7];
    const float* b_proj = (const float*)d_in[8];

    float* out = (float*)d_out;                 // logits then y_pred
    float* ws  = (float*)d_ws;
    float* emb_proj = ws + WS_EMBPROJ;
    float* W_pack   = ws + WS_WPACK;
    float* hs       = ws + WS_HS;
    float* c_buf    = ws + WS_CBUF;
    float* part     = ws + WS_PART;

    k_embproj<<<dim3(32, 16), 256, 0, stream>>>(emb, W_ih, b_ih, b_hh, emb_proj);
    k_pack<<<dim3(4096), 256, 0, stream>>>(W_hh, W_pack);

    for (int t = 0; t < NT; t++)
        k_lstm_step<<<dim3(8, 32), 512, 0, stream>>>(emb_proj, W_pack, x, hs, c_buf, t);

    k_logits<<<dim3(512, 32), 256, 0, stream>>>(hs, W_proj, b_proj, out, part);
    k_argmax<<<dim3(256), 256, 0, stream>>>(part, out + (size_t)65536 * NV);
}